// Round 1
// 1011.899 us; speedup vs baseline: 1.0465x; 1.0465x over previous
//
#include <hip/hip_runtime.h>

// ---------------------------------------------------------------------------
// TTT base module: out = (scan(XC,XB,XA,coeff) ) @ Wo^T
//   XC = hs@Wq^T, XB = hs@Wk^T, XA = hs@Wv^T   (bf16 MFMA GEMMs)
//   coeff from sigmoid(hs@lw^T + lb)           (GEMM with N padded to 128)
//   scan: 128 blocks (B*NH) x 1 wave, W1 state in MFMA accumulators.
//   Scan v3 (latency surgery; single wave, no barriers):
//     - DPP (quad_perm/row_ror) reductions replace 12 shfl_xor levels
//     - bf16-direct LDS staging (no f32 unpack/round-trip)
//     - Attn^T via swapped MFMA operands (sAttn round trip removed)
//     - W1 published to LDS as packed bf16 (cvt_pk), read as fragments
//     - b1 kept in registers (butterfly sum is all-lanes)
//     - coeff read as one aligned float4 per lane (no shfl broadcast)
// ---------------------------------------------------------------------------

typedef __attribute__((ext_vector_type(4))) float float4v;
typedef __attribute__((ext_vector_type(8))) __bf16 bf16x8;
typedef __attribute__((ext_vector_type(4))) short short4v;
typedef __attribute__((ext_vector_type(4))) unsigned int uint4v;
typedef __attribute__((ext_vector_type(2))) unsigned int uint2v;

__device__ __forceinline__ unsigned short f2bf(float f) {
  unsigned int u = __builtin_bit_cast(unsigned int, f);
  u += 0x7FFFu + ((u >> 16) & 1u);
  return (unsigned short)(u >> 16);
}
__device__ __forceinline__ float bf2f(unsigned short s) {
  unsigned int u = ((unsigned int)s) << 16;
  return __builtin_bit_cast(float, u);
}
__device__ __forceinline__ void lds_load16(const void* g, void* l) {
  __builtin_amdgcn_global_load_lds((const __attribute__((address_space(1))) void*)g,
                                   (__attribute__((address_space(3))) void*)l, 16, 0, 0);
}

__device__ __forceinline__ void store_out(float* p, float v) { *p = v; }
__device__ __forceinline__ void store_out(unsigned short* p, float v) { *p = f2bf(v); }

// DPP helpers: VALU-speed cross-lane moves within 16-lane rows.
template <int CTRL>
__device__ __forceinline__ float dppmov(float x) {
  return __builtin_bit_cast(
      float, __builtin_amdgcn_update_dpp(0, __builtin_bit_cast(int, x), CTRL, 0xF, 0xF, true));
}
// Sum over the 16 lanes of a DPP row; result in all 16 lanes.
__device__ __forceinline__ float red16(float x) {
  x += dppmov<0xB1>(x);   // quad_perm [1,0,3,2]  (xor 1)
  x += dppmov<0x4E>(x);   // quad_perm [2,3,0,1]  (xor 2)
  x += dppmov<0x124>(x);  // row_ror:4
  x += dppmov<0x128>(x);  // row_ror:8
  return x;
}
__device__ __forceinline__ unsigned int cvtpk_bf16(float lo, float hi) {
  unsigned int r;
  asm("v_cvt_pk_bf16_f32 %0, %1, %2" : "=v"(r) : "v"(lo), "v"(hi));
  return r;
}

// ---------------------------------------------------------------------------
// C[m,n] = sum_k A[m,k] * B[n,k]   (A: MxK bf16, B: NxK bf16 row-major)
// 128x128 tile, BK=32, 256 threads = 4 waves (2x2 of 64x64), 16x16x32 MFMA.
// ---------------------------------------------------------------------------
template <typename OUT>
__global__ __launch_bounds__(256) void gemm_bt(
    const unsigned short* __restrict__ A, const unsigned short* __restrict__ B,
    OUT* __restrict__ C, int M, int N, int K) {
  __shared__ unsigned short sA[128 * 32];
  __shared__ unsigned short sB[128 * 32];
  const int tid = threadIdx.x;
  const int wave = tid >> 6;
  const int lane = tid & 63;
  const int quad = lane >> 4;
  const int l15 = lane & 15;
  const int wm = (wave >> 1) * 64;
  const int wn = (wave & 1) * 64;
  const int bm = blockIdx.y * 128;
  const int bn = blockIdx.x * 128;

  float4v acc[4][4];
#pragma unroll
  for (int i = 0; i < 4; ++i)
#pragma unroll
    for (int j = 0; j < 4; ++j) acc[i][j] = (float4v){0.f, 0.f, 0.f, 0.f};

  const int srow = tid >> 2;
  const int scol = (tid & 3) * 8;
  const unsigned short* aptr = A + (size_t)(bm + srow) * K + scol;
  const unsigned short* bptr = B + (size_t)(bn + srow) * K + scol;
  unsigned short* sAw0 = &sA[wave * 512];
  unsigned short* sAw1 = &sA[2048 + wave * 512];
  unsigned short* sBw0 = &sB[wave * 512];
  unsigned short* sBw1 = &sB[2048 + wave * 512];
  const size_t astep = (size_t)64 * K;

  for (int kt = 0; kt < K; kt += 32) {
    __syncthreads();
    lds_load16(aptr + kt, sAw0);
    lds_load16(aptr + kt + astep, sAw1);
    lds_load16(bptr + kt, sBw0);
    lds_load16(bptr + kt + astep, sBw1);
    __syncthreads();
    bf16x8 af[4], bf[4];
#pragma unroll
    for (int i = 0; i < 4; ++i)
      af[i] = *(const bf16x8*)&sA[(wm + i * 16 + l15) * 32 + quad * 8];
#pragma unroll
    for (int j = 0; j < 4; ++j)
      bf[j] = *(const bf16x8*)&sB[(wn + j * 16 + l15) * 32 + quad * 8];
#pragma unroll
    for (int i = 0; i < 4; ++i)
#pragma unroll
      for (int j = 0; j < 4; ++j)
        acc[i][j] = __builtin_amdgcn_mfma_f32_16x16x32_bf16(af[i], bf[j], acc[i][j], 0, 0, 0);
  }

#pragma unroll
  for (int i = 0; i < 4; ++i) {
    const int row0 = bm + wm + i * 16 + quad * 4;
#pragma unroll
    for (int j = 0; j < 4; ++j) {
      const int col = bn + wn + j * 16 + l15;
#pragma unroll
      for (int r = 0; r < 4; ++r)
        store_out(&C[(size_t)(row0 + r) * N + col], acc[i][j][r]);
    }
  }
}

// ---------------------------------------------------------------------------
__global__ __launch_bounds__(256) void f32_to_bf16_k(const float* __restrict__ s,
                                                     unsigned short* __restrict__ d, int n) {
  const int i = (blockIdx.x * 256 + threadIdx.x) * 8;
  if (i >= n) return;
  const float4v a = *(const float4v*)(s + i);
  const float4v b = *(const float4v*)(s + i + 4);
  uint4v o;
  o[0] = (unsigned int)f2bf(a[0]) | ((unsigned int)f2bf(a[1]) << 16);
  o[1] = (unsigned int)f2bf(a[2]) | ((unsigned int)f2bf(a[3]) << 16);
  o[2] = (unsigned int)f2bf(b[0]) | ((unsigned int)f2bf(b[1]) << 16);
  o[3] = (unsigned int)f2bf(b[2]) | ((unsigned int)f2bf(b[3]) << 16);
  *(uint4v*)(d + i) = o;
}

// ---------------------------------------------------------------------------
// coeff[b,h,c,k] = sigmoid(ilr[row,h] + lb[h]) / (64*(k+1))
// ---------------------------------------------------------------------------
__global__ __launch_bounds__(256) void coeff_k(const unsigned short* __restrict__ ilr,
                                               const float* __restrict__ lb,
                                               float* __restrict__ coeff) {
  const int gid = blockIdx.x * 256 + threadIdx.x;
  const int row = gid >> 5;
  const int h = gid & 31;
  const float v = bf2f(ilr[row * 128 + h]) + lb[h];
  const float sig = 1.0f / (1.0f + __expf(-v));
  const int b = row >> 11;
  const int pos = row & 2047;
  const int cc = pos >> 4;
  const int k = pos & 15;
  coeff[((((size_t)b * 32 + h) * 128 + cc) << 4) + k] = sig / (64.0f * (float)(k + 1));
}

// ---------------------------------------------------------------------------
// TTT scan v3: one block = one (b,h); 1 wave; 128 sequential chunks of K=16.
// ---------------------------------------------------------------------------
__global__ __launch_bounds__(64, 1) void ttt_scan(
    const unsigned short* __restrict__ XC, const unsigned short* __restrict__ XB,
    const unsigned short* __restrict__ XA, const float* __restrict__ coeff,
    const float* __restrict__ lnw, const float* __restrict__ lnb,
    const float* __restrict__ W1i, const float* __restrict__ b1i,
    unsigned short* __restrict__ XCW) {
  const int b = blockIdx.x >> 5;
  const int h = blockIdx.x & 31;
  const int lane = threadIdx.x;
  const int quad = lane >> 4;
  const int l15 = lane & 15;

  // stride 88 u16 = 176 B: keeps b128 reads 16B-aligned; row step = 44 dwords
  // = 12 banks mod 32 -> max 2-way conflicts (free).
  constexpr int LDW = 88;
  __shared__ unsigned short sW1[64 * LDW];  // [n=f_out][k=f_in] bf16 (= W1^T rows)
  __shared__ unsigned short sXC[16 * LDW];  // [t][f] bf16
  __shared__ unsigned short sXB[16 * LDW];
  __shared__ unsigned short sXA[16 * LDW];

  float gam[4], bet[4];
#pragma unroll
  for (int nt = 0; nt < 4; ++nt) {
    gam[nt] = lnw[h * 64 + nt * 16 + l15];
    bet[nt] = lnb[h * 64 + nt * 16 + l15];
  }
  float4v W1r[16];
#pragma unroll
  for (int mt = 0; mt < 4; ++mt)
#pragma unroll
    for (int nt = 0; nt < 4; ++nt) {
      float4v v;
#pragma unroll
      for (int r = 0; r < 4; ++r)
        v[r] = W1i[(size_t)h * 4096 + (size_t)(mt * 16 + quad * 4 + r) * 64 + nt * 16 + l15];
      W1r[mt * 4 + nt] = v;
    }
  // b1 lives in registers: b1v[nt] = b1[nt*16+l15], replicated across quads.
  float b1v[4];
#pragma unroll
  for (int nt = 0; nt < 4; ++nt) b1v[nt] = b1i[h * 64 + nt * 16 + l15];

  const int srow = lane >> 2;
  const int scol = (lane & 3) * 16;
  const size_t hdoff = (size_t)h * 64;
  const size_t browoff = (size_t)b * 2048;
  const float* cobase = coeff + (((size_t)b * 32 + h) * 128) * 16;
  const float inv64 = 1.0f / 64.0f;
  const float4v zero4 = {0.f, 0.f, 0.f, 0.f};

  // ---- prefetch chunk 0 ----
  uint4v pxc0, pxc1, pxb0, pxb1, pxa0, pxa1;
  float4v pcof;
  {
    const size_t goff = (browoff + (size_t)srow) * 2048 + hdoff + scol;
    pxc0 = *(const uint4v*)(XC + goff);
    pxc1 = *(const uint4v*)(XC + goff + 8);
    pxb0 = *(const uint4v*)(XB + goff);
    pxb1 = *(const uint4v*)(XB + goff + 8);
    pxa0 = *(const uint4v*)(XA + goff);
    pxa1 = *(const uint4v*)(XA + goff + 8);
    pcof = *(const float4v*)(cobase + quad * 4);  // coeff for tokens quad*4+0..3
  }

  for (int c = 0; c < 128; ++c) {
    // consume prefetched chunk
    const uint4v xc0 = pxc0, xc1 = pxc1, xb0 = pxb0, xb1 = pxb1, xa0 = pxa0, xa1 = pxa1;
    const float4v cof = pcof;  // cof[jj] = coeff for token quad*4+jj
    // issue prefetch for next chunk immediately (hidden under compute)
    {
      const int cn = (c < 127) ? c + 1 : 127;
      const size_t goff = (browoff + (size_t)(cn * 16 + srow)) * 2048 + hdoff + scol;
      pxc0 = *(const uint4v*)(XC + goff);
      pxc1 = *(const uint4v*)(XC + goff + 8);
      pxb0 = *(const uint4v*)(XB + goff);
      pxb1 = *(const uint4v*)(XB + goff + 8);
      pxa0 = *(const uint4v*)(XA + goff);
      pxa1 = *(const uint4v*)(XA + goff + 8);
      pcof = *(const float4v*)(cobase + (size_t)cn * 16 + quad * 4);
    }

    // ---- stage current chunk to LDS as raw bf16 (no unpack) ----
    *(uint4v*)&sXC[srow * LDW + scol] = xc0;
    *(uint4v*)&sXC[srow * LDW + scol + 8] = xc1;
    *(uint4v*)&sXB[srow * LDW + scol] = xb0;
    *(uint4v*)&sXB[srow * LDW + scol + 8] = xb1;
    *(uint4v*)&sXA[srow * LDW + scol] = xa0;
    *(uint4v*)&sXA[srow * LDW + scol + 8] = xa1;

    // ---- publish W1 (pre-update) as packed bf16 W1^T ----
#pragma unroll
    for (int mt = 0; mt < 4; ++mt)
#pragma unroll
      for (int nt = 0; nt < 4; ++nt) {
        const float4v w = W1r[mt * 4 + nt];
        uint2v p;
        p[0] = cvtpk_bf16(w[0], w[1]);
        p[1] = cvtpk_bf16(w[2], w[3]);
        *(uint2v*)&sW1[(nt * 16 + l15) * LDW + mt * 16 + quad * 4] = p;
      }

    // ---- fragments: direct bf16x8 reads, zero conversions ----
    bf16x8 xbf[2], xcf[2];
#pragma unroll
    for (int hh = 0; hh < 2; ++hh) {
      xbf[hh] = *(const bf16x8*)&sXB[l15 * LDW + hh * 32 + quad * 8];
      xcf[hh] = *(const bf16x8*)&sXC[l15 * LDW + hh * 32 + quad * 8];
    }
    bf16x8 w1f[4][2];
#pragma unroll
    for (int nt = 0; nt < 4; ++nt)
#pragma unroll
      for (int hh = 0; hh < 2; ++hh)
        w1f[nt][hh] = *(const bf16x8*)&sW1[(nt * 16 + l15) * LDW + hh * 32 + quad * 8];

    // ---- Attn^T = xb@xc^T (swapped operands): at[jj] = Attn[i=l15][j=quad*4+jj]
    //      (independent of W1 -> issued early for MFMA-pipe overlap) ----
    float4v at = __builtin_amdgcn_mfma_f32_16x16x32_bf16(xbf[0], xcf[0], zero4, 0, 0, 0);
    at = __builtin_amdgcn_mfma_f32_16x16x32_bf16(xbf[1], xcf[1], at, 0, 0, 0);

    // ---- Z1 = xb@W1 + b1 ----
    float4v z[4];
#pragma unroll
    for (int nt = 0; nt < 4; ++nt) {
      float4v t = __builtin_amdgcn_mfma_f32_16x16x32_bf16(xbf[0], w1f[nt][0], zero4, 0, 0, 0);
      t = __builtin_amdgcn_mfma_f32_16x16x32_bf16(xbf[1], w1f[nt][1], t, 0, 0, 0);
#pragma unroll
      for (int r = 0; r < 4; ++r) t[r] += b1v[nt];
      z[nt] = t;
    }

    // ---- LN fused L2 backward -> grad (DPP row reductions) ----
    float s1[4], s2[4];
#pragma unroll
    for (int r = 0; r < 4; ++r) {
      s1[r] = red16(z[0][r] + z[1][r] + z[2][r] + z[3][r]);
      s2[r] = red16(z[0][r] * z[0][r] + z[1][r] * z[1][r] + z[2][r] * z[2][r] +
                    z[3][r] * z[3][r]);
    }
    float mu[4], rstd[4];
#pragma unroll
    for (int r = 0; r < 4; ++r) {
      mu[r] = s1[r] * inv64;
      const float var = s2[r] * inv64 - mu[r] * mu[r];
      rstd[r] = rsqrtf(var + 1e-6f);
    }
    float xh[4][4], gg[4][4];
#pragma unroll
    for (int nt = 0; nt < 4; ++nt)
#pragma unroll
      for (int r = 0; r < 4; ++r) {
        const float xhat = (z[nt][r] - mu[r]) * rstd[r];
        xh[nt][r] = xhat;
        const float y = gam[nt] * xhat + bet[nt];
        const int toff = (quad * 4 + r) * LDW + nt * 16 + l15;
        const float tgt = bf2f(sXA[toff]) - bf2f(sXB[toff]);
        gg[nt][r] = (y - tgt) * gam[nt];
      }
    float sg[4], sgx[4];
#pragma unroll
    for (int r = 0; r < 4; ++r) {
      sg[r] = red16(gg[0][r] + gg[1][r] + gg[2][r] + gg[3][r]);
      sgx[r] = red16(gg[0][r] * xh[0][r] + gg[1][r] * xh[1][r] + gg[2][r] * xh[2][r] +
                     gg[3][r] * xh[3][r]);
    }
    float grad[4][4];
    short4v gradb[4];
#pragma unroll
    for (int nt = 0; nt < 4; ++nt)
#pragma unroll
      for (int r = 0; r < 4; ++r) {
        grad[nt][r] = (64.0f * gg[nt][r] - sg[r] - xh[nt][r] * sgx[r]) * (rstd[r] * inv64);
        gradb[nt][r] = (short)f2bf(grad[nt][r]);
      }

    // ---- m1f = -(Attn+1) o E  (A-frag: lane=row i, k=quad*4+jj) ----
    short4v m1f;
#pragma unroll
    for (int jj = 0; jj < 4; ++jj) {
      const int k = quad * 4 + jj;
      const float e = (k <= l15) ? cof[jj] : 0.0f;
      m1f[jj] = (short)f2bf(-(at[jj] + 1.0f) * e);
    }

    // ---- Z1_bar = xc@W1 - ((Attn+1) o E)@grad + b1 ----
#pragma unroll
    for (int nt = 0; nt < 4; ++nt) {
      float4v t = __builtin_amdgcn_mfma_f32_16x16x32_bf16(xcf[0], w1f[nt][0], zero4, 0, 0, 0);
      t = __builtin_amdgcn_mfma_f32_16x16x32_bf16(xcf[1], w1f[nt][1], t, 0, 0, 0);
      t = __builtin_amdgcn_mfma_f32_16x16x16bf16_1k(m1f, gradb[nt], t, 0, 0, 0);
#pragma unroll
      for (int r = 0; r < 4; ++r) t[r] += b1v[nt];
      z[nt] = t;
    }

    // ---- out = xc + LN(Z1_bar) ----
#pragma unroll
    for (int r = 0; r < 4; ++r) {
      s1[r] = red16(z[0][r] + z[1][r] + z[2][r] + z[3][r]);
      s2[r] = red16(z[0][r] * z[0][r] + z[1][r] * z[1][r] + z[2][r] * z[2][r] +
                    z[3][r] * z[3][r]);
    }
#pragma unroll
    for (int r = 0; r < 4; ++r) {
      mu[r] = s1[r] * inv64;
      const float var = s2[r] * inv64 - mu[r] * mu[r];
      rstd[r] = rsqrtf(var + 1e-6f);
    }
#pragma unroll
    for (int nt = 0; nt < 4; ++nt)
#pragma unroll
      for (int r = 0; r < 4; ++r) {
        const float xhat = (z[nt][r] - mu[r]) * rstd[r];
        const float y = gam[nt] * xhat + bet[nt];
        const float o = bf2f(sXC[(quad * 4 + r) * LDW + nt * 16 + l15]) + y;
        XCW[(browoff + (size_t)(c * 16 + quad * 4 + r)) * 2048 + hdoff + nt * 16 + l15] = f2bf(o);
      }

    // ---- b1 -= sum_t co_t * grad[t][:]  (f32; butterfly -> all lanes) ----
#pragma unroll
    for (int nt = 0; nt < 4; ++nt) {
      float pb = cof[0] * grad[nt][0] + cof[1] * grad[nt][1] + cof[2] * grad[nt][2] +
                 cof[3] * grad[nt][3];
      pb += __shfl_xor(pb, 16);
      pb += __shfl_xor(pb, 32);
      b1v[nt] -= pb;
    }

    // ---- W1 -= (co o xb)^T @ grad ----
#pragma unroll
    for (int mt = 0; mt < 4; ++mt) {
      short4v caf;
#pragma unroll
      for (int jj = 0; jj < 4; ++jj)
        caf[jj] = (short)f2bf(-cof[jj] * bf2f(sXB[(quad * 4 + jj) * LDW + mt * 16 + l15]));
#pragma unroll
      for (int nt = 0; nt < 4; ++nt)
        W1r[mt * 4 + nt] =
            __builtin_amdgcn_mfma_f32_16x16x16bf16_1k(caf, gradb[nt], W1r[mt * 4 + nt], 0, 0, 0);
    }
  }
}

// ---------------------------------------------------------------------------
extern "C" void kernel_launch(void* const* d_in, const int* in_sizes, int n_in,
                              void* d_out, int out_size, void* d_ws, size_t ws_size,
                              hipStream_t stream) {
  const float* hs = (const float*)d_in[0];
  const float* Wq = (const float*)d_in[1];
  const float* Wk = (const float*)d_in[2];
  const float* Wv = (const float*)d_in[3];
  const float* Wo = (const float*)d_in[4];
  const float* lw = (const float*)d_in[5];
  const float* lb = (const float*)d_in[6];
  const float* lnw = (const float*)d_in[7];
  const float* lnb = (const float*)d_in[8];
  const float* W1i = (const float*)d_in[9];
  const float* b1i = (const float*)d_in[10];
  float* out = (float*)d_out;
  char* ws = (char*)d_ws;

  unsigned short* hsb = (unsigned short*)(ws);               // 33554432 (hs bf16; reused as XCW)
  unsigned short* wqb = (unsigned short*)(ws + 33554432);    // 8388608
  unsigned short* wkb = (unsigned short*)(ws + 41943040);    // 8388608
  unsigned short* wvb = (unsigned short*)(ws + 50331648);    // 8388608
  unsigned short* wob = (unsigned short*)(ws + 58720256);    // 8388608
  unsigned short* lwb = (unsigned short*)(ws + 67108864);    // 524288
  unsigned short* XCb = (unsigned short*)(ws + 67633152);    // 33554432
  unsigned short* XBb = (unsigned short*)(ws + 101187584);   // 33554432
  unsigned short* XAb = (unsigned short*)(ws + 134742016);   // 33554432
  unsigned short* ilrb = (unsigned short*)(ws + 168296448);  // 2097152
  float* coeff = (float*)(ws + 170393600);                   // 1048576

  f32_to_bf16_k<<<8192, 256, 0, stream>>>(hs, hsb, 16777216);
  f32_to_bf16_k<<<2048, 256, 0, stream>>>(Wq, wqb, 4194304);
  f32_to_bf16_k<<<2048, 256, 0, stream>>>(Wk, wkb, 4194304);
  f32_to_bf16_k<<<2048, 256, 0, stream>>>(Wv, wvb, 4194304);
  f32_to_bf16_k<<<2048, 256, 0, stream>>>(Wo, wob, 4194304);
  hipMemsetAsync(lwb, 0, 524288, stream);
  f32_to_bf16_k<<<32, 256, 0, stream>>>(lw, lwb, 65536);

  dim3 blk(256);
  dim3 gbig(16, 64);
  gemm_bt<unsigned short><<<gbig, blk, 0, stream>>>(hsb, wqb, XCb, 8192, 2048, 2048);
  gemm_bt<unsigned short><<<gbig, blk, 0, stream>>>(hsb, wkb, XBb, 8192, 2048, 2048);
  gemm_bt<unsigned short><<<gbig, blk, 0, stream>>>(hsb, wvb, XAb, 8192, 2048, 2048);
  gemm_bt<unsigned short><<<dim3(1, 64), blk, 0, stream>>>(hsb, lwb, ilrb, 8192, 128, 2048);
  coeff_k<<<1024, 256, 0, stream>>>(ilrb, lb, coeff);
  ttt_scan<<<128, 64, 0, stream>>>(XCb, XBb, XAb, coeff, lnw, lnb, W1i, b1i, hsb);
  gemm_bt<float><<<gbig, blk, 0, stream>>>(hsb, wob, out, 8192, 2048, 2048);
}

// Round 2
// 926.085 us; speedup vs baseline: 1.1434x; 1.0927x over previous
//
#include <hip/hip_runtime.h>

// ---------------------------------------------------------------------------
// TTT base module: out = (scan(XC,XB,XA,coeff) ) @ Wo^T
//   XC = hs@Wq^T, XB = hs@Wk^T, XA = hs@Wv^T   (bf16 MFMA GEMMs)
//   coeff from sigmoid(hs@lw^T + lb)           (GEMM with N padded to 128)
//   Scan v4: 128 blocks x 4 waves. Feature dim (64) split across waves:
//     wave w owns output features w*16..w*16+15 (W1 columns, Z1/Z1bar tile,
//     grad slice, b1 slice, out slice). Cross-wave coupling only at the three
//     per-token reductions (LN1, grad-sums, LN2): in-wave red16 -> float2 LDS
//     write -> raw s_barrier (+lgkmcnt only; no vmcnt drain) -> b128 combine.
//     W1 LDS rows are wave-private (publish end of iter, read next iter).
//     Global prefetch of chunk c+1 issued right after the stage barrier and
//     never drained until consumed (raw barriers skip the vmcnt(0) drain).
// ---------------------------------------------------------------------------

typedef __attribute__((ext_vector_type(4))) float float4v;
typedef __attribute__((ext_vector_type(2))) float float2v;
typedef __attribute__((ext_vector_type(8))) __bf16 bf16x8;
typedef __attribute__((ext_vector_type(4))) short short4v;
typedef __attribute__((ext_vector_type(4))) unsigned int uint4v;
typedef __attribute__((ext_vector_type(2))) unsigned int uint2v;

__device__ __forceinline__ unsigned short f2bf(float f) {
  unsigned int u = __builtin_bit_cast(unsigned int, f);
  u += 0x7FFFu + ((u >> 16) & 1u);
  return (unsigned short)(u >> 16);
}
__device__ __forceinline__ float bf2f(unsigned short s) {
  unsigned int u = ((unsigned int)s) << 16;
  return __builtin_bit_cast(float, u);
}
__device__ __forceinline__ void lds_load16(const void* g, void* l) {
  __builtin_amdgcn_global_load_lds((const __attribute__((address_space(1))) void*)g,
                                   (__attribute__((address_space(3))) void*)l, 16, 0, 0);
}

__device__ __forceinline__ void store_out(float* p, float v) { *p = v; }
__device__ __forceinline__ void store_out(unsigned short* p, float v) { *p = f2bf(v); }

// DPP helpers: VALU-speed cross-lane moves within 16-lane rows.
template <int CTRL>
__device__ __forceinline__ float dppmov(float x) {
  return __builtin_bit_cast(
      float, __builtin_amdgcn_update_dpp(0, __builtin_bit_cast(int, x), CTRL, 0xF, 0xF, true));
}
// Sum over the 16 lanes of a DPP row; result in all 16 lanes.
__device__ __forceinline__ float red16(float x) {
  x += dppmov<0xB1>(x);   // quad_perm [1,0,3,2]  (xor 1)
  x += dppmov<0x4E>(x);   // quad_perm [2,3,0,1]  (xor 2)
  x += dppmov<0x124>(x);  // row_ror:4
  x += dppmov<0x128>(x);  // row_ror:8
  return x;
}
__device__ __forceinline__ unsigned int cvtpk_bf16(float lo, float hi) {
  unsigned int r;
  asm("v_cvt_pk_bf16_f32 %0, %1, %2" : "=v"(r) : "v"(lo), "v"(hi));
  return r;
}
// Raw workgroup barrier: waits only LDS ops (lgkmcnt), NOT vmcnt -> in-flight
// global prefetch survives the barrier (m201-verified pattern).
__device__ __forceinline__ void bar_sync() {
  asm volatile("s_waitcnt lgkmcnt(0)" ::: "memory");
  __builtin_amdgcn_s_barrier();
  asm volatile("" ::: "memory");
}

// ---------------------------------------------------------------------------
// C[m,n] = sum_k A[m,k] * B[n,k]   (A: MxK bf16, B: NxK bf16 row-major)
// 128x128 tile, BK=32, 256 threads = 4 waves (2x2 of 64x64), 16x16x32 MFMA.
// ---------------------------------------------------------------------------
template <typename OUT>
__global__ __launch_bounds__(256) void gemm_bt(
    const unsigned short* __restrict__ A, const unsigned short* __restrict__ B,
    OUT* __restrict__ C, int M, int N, int K) {
  __shared__ unsigned short sA[128 * 32];
  __shared__ unsigned short sB[128 * 32];
  const int tid = threadIdx.x;
  const int wave = tid >> 6;
  const int lane = tid & 63;
  const int quad = lane >> 4;
  const int l15 = lane & 15;
  const int wm = (wave >> 1) * 64;
  const int wn = (wave & 1) * 64;
  const int bm = blockIdx.y * 128;
  const int bn = blockIdx.x * 128;

  float4v acc[4][4];
#pragma unroll
  for (int i = 0; i < 4; ++i)
#pragma unroll
    for (int j = 0; j < 4; ++j) acc[i][j] = (float4v){0.f, 0.f, 0.f, 0.f};

  const int srow = tid >> 2;
  const int scol = (tid & 3) * 8;
  const unsigned short* aptr = A + (size_t)(bm + srow) * K + scol;
  const unsigned short* bptr = B + (size_t)(bn + srow) * K + scol;
  unsigned short* sAw0 = &sA[wave * 512];
  unsigned short* sAw1 = &sA[2048 + wave * 512];
  unsigned short* sBw0 = &sB[wave * 512];
  unsigned short* sBw1 = &sB[2048 + wave * 512];
  const size_t astep = (size_t)64 * K;

  for (int kt = 0; kt < K; kt += 32) {
    __syncthreads();
    lds_load16(aptr + kt, sAw0);
    lds_load16(aptr + kt + astep, sAw1);
    lds_load16(bptr + kt, sBw0);
    lds_load16(bptr + kt + astep, sBw1);
    __syncthreads();
    bf16x8 af[4], bf[4];
#pragma unroll
    for (int i = 0; i < 4; ++i)
      af[i] = *(const bf16x8*)&sA[(wm + i * 16 + l15) * 32 + quad * 8];
#pragma unroll
    for (int j = 0; j < 4; ++j)
      bf[j] = *(const bf16x8*)&sB[(wn + j * 16 + l15) * 32 + quad * 8];
#pragma unroll
    for (int i = 0; i < 4; ++i)
#pragma unroll
      for (int j = 0; j < 4; ++j)
        acc[i][j] = __builtin_amdgcn_mfma_f32_16x16x32_bf16(af[i], bf[j], acc[i][j], 0, 0, 0);
  }

#pragma unroll
  for (int i = 0; i < 4; ++i) {
    const int row0 = bm + wm + i * 16 + quad * 4;
#pragma unroll
    for (int j = 0; j < 4; ++j) {
      const int col = bn + wn + j * 16 + l15;
#pragma unroll
      for (int r = 0; r < 4; ++r)
        store_out(&C[(size_t)(row0 + r) * N + col], acc[i][j][r]);
    }
  }
}

// ---------------------------------------------------------------------------
__global__ __launch_bounds__(256) void f32_to_bf16_k(const float* __restrict__ s,
                                                     unsigned short* __restrict__ d, int n) {
  const int i = (blockIdx.x * 256 + threadIdx.x) * 8;
  if (i >= n) return;
  const float4v a = *(const float4v*)(s + i);
  const float4v b = *(const float4v*)(s + i + 4);
  uint4v o;
  o[0] = (unsigned int)f2bf(a[0]) | ((unsigned int)f2bf(a[1]) << 16);
  o[1] = (unsigned int)f2bf(a[2]) | ((unsigned int)f2bf(a[3]) << 16);
  o[2] = (unsigned int)f2bf(b[0]) | ((unsigned int)f2bf(b[1]) << 16);
  o[3] = (unsigned int)f2bf(b[2]) | ((unsigned int)f2bf(b[3]) << 16);
  *(uint4v*)(d + i) = o;
}

// ---------------------------------------------------------------------------
// coeff[b,h,c,k] = sigmoid(ilr[row,h] + lb[h]) / (64*(k+1))
// ---------------------------------------------------------------------------
__global__ __launch_bounds__(256) void coeff_k(const unsigned short* __restrict__ ilr,
                                               const float* __restrict__ lb,
                                               float* __restrict__ coeff) {
  const int gid = blockIdx.x * 256 + threadIdx.x;
  const int row = gid >> 5;
  const int h = gid & 31;
  const float v = bf2f(ilr[row * 128 + h]) + lb[h];
  const float sig = 1.0f / (1.0f + __expf(-v));
  const int b = row >> 11;
  const int pos = row & 2047;
  const int cc = pos >> 4;
  const int k = pos & 15;
  coeff[((((size_t)b * 32 + h) * 128 + cc) << 4) + k] = sig / (64.0f * (float)(k + 1));
}

// ---------------------------------------------------------------------------
// TTT scan v4: one block = one (b,h); 4 waves; 128 sequential chunks of K=16.
// Wave w owns features w*16..w*16+15.
// ---------------------------------------------------------------------------
__global__ __launch_bounds__(256, 1) void ttt_scan(
    const unsigned short* __restrict__ XC, const unsigned short* __restrict__ XB,
    const unsigned short* __restrict__ XA, const float* __restrict__ coeff,
    const float* __restrict__ lnw, const float* __restrict__ lnb,
    const float* __restrict__ W1i, const float* __restrict__ b1i,
    unsigned short* __restrict__ XCW) {
  const int b = blockIdx.x >> 5;
  const int h = blockIdx.x & 31;
  const int tid = threadIdx.x;
  const int wave = tid >> 6;
  const int lane = tid & 63;
  const int quad = lane >> 4;
  const int l15 = lane & 15;

  // stride 88 u16 = 176 B: b128 reads stay 16B-aligned; row step = 44 dwords
  // = 12 banks mod 32 -> max 2-way conflicts (free).
  constexpr int LDW = 88;
  __shared__ __attribute__((aligned(16))) unsigned short sXC[2][16 * LDW];
  __shared__ __attribute__((aligned(16))) unsigned short sXB[2][16 * LDW];
  __shared__ __attribute__((aligned(16))) unsigned short sXA[2][16 * LDW];
  __shared__ __attribute__((aligned(16))) unsigned short sW1[64 * LDW];
  __shared__ __attribute__((aligned(16))) float sRed[3][16][8];  // [stage][token][wave*2+{a,b}]

  const int fcol = wave * 16 + l15;  // this lane's owned feature
  const float gam = lnw[h * 64 + fcol];
  const float bet = lnb[h * 64 + fcol];

  // W1 columns owned by this wave: W1r[mt][r] = W1[mt*16+quad*4+r][fcol]
  float4v W1r[4];
#pragma unroll
  for (int mt = 0; mt < 4; ++mt) {
    float4v v;
#pragma unroll
    for (int r = 0; r < 4; ++r)
      v[r] = W1i[(size_t)h * 4096 + (size_t)(mt * 16 + quad * 4 + r) * 64 + fcol];
    W1r[mt] = v;
  }
  float b1v = b1i[h * 64 + fcol];

  // initial publish of W1^T rows (wave-private rows [wave*16+l15])
#pragma unroll
  for (int mt = 0; mt < 4; ++mt) {
    uint2v p;
    p[0] = cvtpk_bf16(W1r[mt][0], W1r[mt][1]);
    p[1] = cvtpk_bf16(W1r[mt][2], W1r[mt][3]);
    *(uint2v*)&sW1[(size_t)fcol * LDW + mt * 16 + quad * 4] = p;
  }

  // staging unit: 16 rows x 8 col-chunks of 16B per tensor; threads 0-127
  // cover XC+XA, threads 128-255 cover XB.
  const int u = tid & 127;
  const int grow = u >> 3;
  const int gcol = (u & 7) * 8;
  const size_t hdoff = (size_t)h * 64;
  const size_t browoff = (size_t)b * 2048;
  const float* cobase = coeff + (((size_t)b * 32 + h) * 128) * 16;
  const float inv64 = 1.0f / 64.0f;
  const float4v zero4 = {0.f, 0.f, 0.f, 0.f};

  // ---- prefetch chunk 0 ----
  uint4v pA = {0, 0, 0, 0}, pB = {0, 0, 0, 0};
  float4v pcof;
  {
    const size_t goff = (browoff + (size_t)grow) * 2048 + hdoff + gcol;
    if (tid < 128) {
      pA = *(const uint4v*)(XC + goff);
      pB = *(const uint4v*)(XA + goff);
    } else {
      pA = *(const uint4v*)(XB + goff);
    }
    pcof = *(const float4v*)(cobase + quad * 4);  // coeff for tokens quad*4+0..3
  }

  for (int c = 0; c < 128; ++c) {
    const int buf = c & 1;
    // ---- write staged regs to LDS (vmcnt waits inserted by data dep) ----
    if (tid < 128) {
      *(uint4v*)&sXC[buf][grow * LDW + gcol] = pA;
      *(uint4v*)&sXA[buf][grow * LDW + gcol] = pB;
    } else {
      *(uint4v*)&sXB[buf][grow * LDW + gcol] = pA;
    }
    const float4v cof = pcof;  // cof[jj] = coeff for token quad*4+jj
    bar_sync();  // stage(c) + W1 publish visible

    // ---- issue prefetch for chunk c+1 (survives raw barriers) ----
    {
      const int cn = (c < 127) ? c + 1 : 127;
      const size_t goff = (browoff + (size_t)(cn * 16 + grow)) * 2048 + hdoff + gcol;
      if (tid < 128) {
        pA = *(const uint4v*)(XC + goff);
        pB = *(const uint4v*)(XA + goff);
      } else {
        pA = *(const uint4v*)(XB + goff);
      }
      pcof = *(const float4v*)(cobase + (size_t)cn * 16 + quad * 4);
    }

    // ---- fragments ----
    bf16x8 xbf[2], xcf[2], w1f[2];
#pragma unroll
    for (int hh = 0; hh < 2; ++hh) {
      xbf[hh] = *(const bf16x8*)&sXB[buf][l15 * LDW + hh * 32 + quad * 8];
      xcf[hh] = *(const bf16x8*)&sXC[buf][l15 * LDW + hh * 32 + quad * 8];
      w1f[hh] = *(const bf16x8*)&sW1[(size_t)fcol * LDW + hh * 32 + quad * 8];
    }

    // ---- Z1 = xb@W1[:,wave cols] + b1 ----
    float4v z = __builtin_amdgcn_mfma_f32_16x16x32_bf16(xbf[0], w1f[0], zero4, 0, 0, 0);
    z = __builtin_amdgcn_mfma_f32_16x16x32_bf16(xbf[1], w1f[1], z, 0, 0, 0);
#pragma unroll
    for (int r = 0; r < 4; ++r) z[r] += b1v;

    // ---- LN1 partials (per-wave feature slice) ----
    float s1p[4], s2p[4];
#pragma unroll
    for (int r = 0; r < 4; ++r) {
      s1p[r] = red16(z[r]);
      s2p[r] = red16(z[r] * z[r]);
    }
    if (l15 == 0) {
#pragma unroll
      for (int r = 0; r < 4; ++r)
        *(float2v*)&sRed[0][quad * 4 + r][wave * 2] = (float2v){s1p[r], s2p[r]};
    }

    // ---- Attn^T = xb@xc^T (indep of W1; hides under bar) ----
    float4v at = __builtin_amdgcn_mfma_f32_16x16x32_bf16(xbf[0], xcf[0], zero4, 0, 0, 0);
    at = __builtin_amdgcn_mfma_f32_16x16x32_bf16(xbf[1], xcf[1], at, 0, 0, 0);

    bar_sync();  // red1 partials visible

    float mu[4], rstd[4];
#pragma unroll
    for (int r = 0; r < 4; ++r) {
      const float4v v0 = *(const float4v*)&sRed[0][quad * 4 + r][0];
      const float4v v1 = *(const float4v*)&sRed[0][quad * 4 + r][4];
      const float s1 = v0[0] + v0[2] + v1[0] + v1[2];
      const float s2 = v0[1] + v0[3] + v1[1] + v1[3];
      mu[r] = s1 * inv64;
      rstd[r] = rsqrtf(s2 * inv64 - mu[r] * mu[r] + 1e-6f);
    }
    float xh[4], gg[4];
#pragma unroll
    for (int r = 0; r < 4; ++r) {
      xh[r] = (z[r] - mu[r]) * rstd[r];
      const int toff = (quad * 4 + r) * LDW + fcol;
      const float tgt = bf2f(sXA[buf][toff]) - bf2f(sXB[buf][toff]);
      gg[r] = (gam * xh[r] + bet - tgt) * gam;
    }
    float sgp[4], sgxp[4];
#pragma unroll
    for (int r = 0; r < 4; ++r) {
      sgp[r] = red16(gg[r]);
      sgxp[r] = red16(gg[r] * xh[r]);
    }
    if (l15 == 0) {
#pragma unroll
      for (int r = 0; r < 4; ++r)
        *(float2v*)&sRed[1][quad * 4 + r][wave * 2] = (float2v){sgp[r], sgxp[r]};
    }

    // ---- indep work under bar2: caf (W1-update A-frag), m1f ----
    short4v caf[4];
#pragma unroll
    for (int mt = 0; mt < 4; ++mt)
#pragma unroll
      for (int jj = 0; jj < 4; ++jj)
        caf[mt][jj] =
            (short)f2bf(-cof[jj] * bf2f(sXB[buf][(quad * 4 + jj) * LDW + mt * 16 + l15]));
    short4v m1f;
#pragma unroll
    for (int jj = 0; jj < 4; ++jj) {
      const int k = quad * 4 + jj;
      const float e = (k <= l15) ? cof[jj] : 0.0f;
      m1f[jj] = (short)f2bf(-(at[jj] + 1.0f) * e);
    }

    bar_sync();  // red2 partials visible

    float grad[4];
    short4v gradb;
#pragma unroll
    for (int r = 0; r < 4; ++r) {
      const float4v v0 = *(const float4v*)&sRed[1][quad * 4 + r][0];
      const float4v v1 = *(const float4v*)&sRed[1][quad * 4 + r][4];
      const float sg = v0[0] + v0[2] + v1[0] + v1[2];
      const float sgx = v0[1] + v0[3] + v1[1] + v1[3];
      grad[r] = (64.0f * gg[r] - sg - xh[r] * sgx) * (rstd[r] * inv64);
      gradb[r] = (short)f2bf(grad[r]);
    }

    // ---- Z1_bar = xc@W1 - ((Attn+1) o E)@grad + b1 (old b1) ----
    float4v zb = __builtin_amdgcn_mfma_f32_16x16x32_bf16(xcf[0], w1f[0], zero4, 0, 0, 0);
    zb = __builtin_amdgcn_mfma_f32_16x16x32_bf16(xcf[1], w1f[1], zb, 0, 0, 0);
    zb = __builtin_amdgcn_mfma_f32_16x16x16bf16_1k(m1f, gradb, zb, 0, 0, 0);
#pragma unroll
    for (int r = 0; r < 4; ++r) zb[r] += b1v;

    // ---- LN2 partials ----
#pragma unroll
    for (int r = 0; r < 4; ++r) {
      s1p[r] = red16(zb[r]);
      s2p[r] = red16(zb[r] * zb[r]);
    }
    if (l15 == 0) {
#pragma unroll
      for (int r = 0; r < 4; ++r)
        *(float2v*)&sRed[2][quad * 4 + r][wave * 2] = (float2v){s1p[r], s2p[r]};
    }

    // ---- indep work under bar3: b1 update + W1 update MFMAs ----
    {
      float pb = cof[0] * grad[0] + cof[1] * grad[1] + cof[2] * grad[2] + cof[3] * grad[3];
      pb += __shfl_xor(pb, 16);
      pb += __shfl_xor(pb, 32);
      b1v -= pb;
    }
#pragma unroll
    for (int mt = 0; mt < 4; ++mt)
      W1r[mt] = __builtin_amdgcn_mfma_f32_16x16x16bf16_1k(caf[mt], gradb, W1r[mt], 0, 0, 0);

    bar_sync();  // red3 partials visible

#pragma unroll
    for (int r = 0; r < 4; ++r) {
      const float4v v0 = *(const float4v*)&sRed[2][quad * 4 + r][0];
      const float4v v1 = *(const float4v*)&sRed[2][quad * 4 + r][4];
      const float s1 = v0[0] + v0[2] + v1[0] + v1[2];
      const float s2 = v0[1] + v0[3] + v1[1] + v1[3];
      const float mu2 = s1 * inv64;
      const float rstd2 = rsqrtf(s2 * inv64 - mu2 * mu2 + 1e-6f);
      const float xhat = (zb[r] - mu2) * rstd2;
      const float y = gam * xhat + bet;
      const float o = bf2f(sXC[buf][(quad * 4 + r) * LDW + fcol]) + y;
      XCW[(browoff + (size_t)(c * 16 + quad * 4 + r)) * 2048 + hdoff + fcol] = f2bf(o);
    }

    // ---- publish updated W1 for next chunk (wave-private rows) ----
#pragma unroll
    for (int mt = 0; mt < 4; ++mt) {
      uint2v p;
      p[0] = cvtpk_bf16(W1r[mt][0], W1r[mt][1]);
      p[1] = cvtpk_bf16(W1r[mt][2], W1r[mt][3]);
      *(uint2v*)&sW1[(size_t)fcol * LDW + mt * 16 + quad * 4] = p;
    }
  }
}

// ---------------------------------------------------------------------------
extern "C" void kernel_launch(void* const* d_in, const int* in_sizes, int n_in,
                              void* d_out, int out_size, void* d_ws, size_t ws_size,
                              hipStream_t stream) {
  const float* hs = (const float*)d_in[0];
  const float* Wq = (const float*)d_in[1];
  const float* Wk = (const float*)d_in[2];
  const float* Wv = (const float*)d_in[3];
  const float* Wo = (const float*)d_in[4];
  const float* lw = (const float*)d_in[5];
  const float* lb = (const float*)d_in[6];
  const float* lnw = (const float*)d_in[7];
  const float* lnb = (const float*)d_in[8];
  const float* W1i = (const float*)d_in[9];
  const float* b1i = (const float*)d_in[10];
  float* out = (float*)d_out;
  char* ws = (char*)d_ws;

  unsigned short* hsb = (unsigned short*)(ws);               // 33554432 (hs bf16; reused as XCW)
  unsigned short* wqb = (unsigned short*)(ws + 33554432);    // 8388608
  unsigned short* wkb = (unsigned short*)(ws + 41943040);    // 8388608
  unsigned short* wvb = (unsigned short*)(ws + 50331648);    // 8388608
  unsigned short* wob = (unsigned short*)(ws + 58720256);    // 8388608
  unsigned short* lwb = (unsigned short*)(ws + 67108864);    // 524288
  unsigned short* XCb = (unsigned short*)(ws + 67633152);    // 33554432
  unsigned short* XBb = (unsigned short*)(ws + 101187584);   // 33554432
  unsigned short* XAb = (unsigned short*)(ws + 134742016);   // 33554432
  unsigned short* ilrb = (unsigned short*)(ws + 168296448);  // 2097152
  float* coeff = (float*)(ws + 170393600);                   // 1048576

  f32_to_bf16_k<<<8192, 256, 0, stream>>>(hs, hsb, 16777216);
  f32_to_bf16_k<<<2048, 256, 0, stream>>>(Wq, wqb, 4194304);
  f32_to_bf16_k<<<2048, 256, 0, stream>>>(Wk, wkb, 4194304);
  f32_to_bf16_k<<<2048, 256, 0, stream>>>(Wv, wvb, 4194304);
  f32_to_bf16_k<<<2048, 256, 0, stream>>>(Wo, wob, 4194304);
  hipMemsetAsync(lwb, 0, 524288, stream);
  f32_to_bf16_k<<<32, 256, 0, stream>>>(lw, lwb, 65536);

  dim3 blk(256);
  dim3 gbig(16, 64);
  gemm_bt<unsigned short><<<gbig, blk, 0, stream>>>(hsb, wqb, XCb, 8192, 2048, 2048);
  gemm_bt<unsigned short><<<gbig, blk, 0, stream>>>(hsb, wkb, XBb, 8192, 2048, 2048);
  gemm_bt<unsigned short><<<gbig, blk, 0, stream>>>(hsb, wvb, XAb, 8192, 2048, 2048);
  gemm_bt<unsigned short><<<dim3(1, 64), blk, 0, stream>>>(hsb, lwb, ilrb, 8192, 128, 2048);
  coeff_k<<<1024, 256, 0, stream>>>(ilrb, lb, coeff);
  ttt_scan<<<128, 256, 0, stream>>>(XCb, XBb, XAb, coeff, lnw, lnb, W1i, b1i, hsb);
  gemm_bt<float><<<gbig, blk, 0, stream>>>(hsb, wob, out, 8192, 2048, 2048);
}

// Round 3
// 872.006 us; speedup vs baseline: 1.2143x; 1.0620x over previous
//
#include <hip/hip_runtime.h>

// ---------------------------------------------------------------------------
// TTT base module: out = (scan(XC,XB,XA,coeff) ) @ Wo^T
//   XC = hs@Wq^T, XB = hs@Wk^T, XA = hs@Wv^T   (bf16 MFMA GEMMs)
//   coeff from sigmoid(hs@lw^T + lb)           (GEMM with N padded to 128)
//   GEMM v2: 128x128 tile, BK=32, 2-phase double-buffered LDS:
//     issue next-tile global_load_lds BEFORE ds_read+MFMA of current tile,
//     single vmcnt(0)+raw-barrier per K-step (T3 minimum-2-phase recipe).
//   Scan v4 (unchanged this round): 4 waves, feature-split, raw barriers.
// ---------------------------------------------------------------------------

typedef __attribute__((ext_vector_type(4))) float float4v;
typedef __attribute__((ext_vector_type(2))) float float2v;
typedef __attribute__((ext_vector_type(8))) __bf16 bf16x8;
typedef __attribute__((ext_vector_type(4))) short short4v;
typedef __attribute__((ext_vector_type(4))) unsigned int uint4v;
typedef __attribute__((ext_vector_type(2))) unsigned int uint2v;

__device__ __forceinline__ unsigned short f2bf(float f) {
  unsigned int u = __builtin_bit_cast(unsigned int, f);
  u += 0x7FFFu + ((u >> 16) & 1u);
  return (unsigned short)(u >> 16);
}
__device__ __forceinline__ float bf2f(unsigned short s) {
  unsigned int u = ((unsigned int)s) << 16;
  return __builtin_bit_cast(float, u);
}
__device__ __forceinline__ void lds_load16(const void* g, void* l) {
  __builtin_amdgcn_global_load_lds((const __attribute__((address_space(1))) void*)g,
                                   (__attribute__((address_space(3))) void*)l, 16, 0, 0);
}

__device__ __forceinline__ void store_out(float* p, float v) { *p = v; }
__device__ __forceinline__ void store_out(unsigned short* p, float v) { *p = f2bf(v); }

// DPP helpers: VALU-speed cross-lane moves within 16-lane rows.
template <int CTRL>
__device__ __forceinline__ float dppmov(float x) {
  return __builtin_bit_cast(
      float, __builtin_amdgcn_update_dpp(0, __builtin_bit_cast(int, x), CTRL, 0xF, 0xF, true));
}
// Sum over the 16 lanes of a DPP row; result in all 16 lanes.
__device__ __forceinline__ float red16(float x) {
  x += dppmov<0xB1>(x);   // quad_perm [1,0,3,2]  (xor 1)
  x += dppmov<0x4E>(x);   // quad_perm [2,3,0,1]  (xor 2)
  x += dppmov<0x124>(x);  // row_ror:4
  x += dppmov<0x128>(x);  // row_ror:8
  return x;
}
__device__ __forceinline__ unsigned int cvtpk_bf16(float lo, float hi) {
  unsigned int r;
  asm("v_cvt_pk_bf16_f32 %0, %1, %2" : "=v"(r) : "v"(lo), "v"(hi));
  return r;
}
// Raw workgroup barrier: waits only LDS ops (lgkmcnt), NOT vmcnt -> in-flight
// global prefetch survives the barrier (m201-verified pattern).
__device__ __forceinline__ void bar_sync() {
  asm volatile("s_waitcnt lgkmcnt(0)" ::: "memory");
  __builtin_amdgcn_s_barrier();
  asm volatile("" ::: "memory");
}
// GEMM barrier pair: wait staged loads, then sync (one per K-step).
__device__ __forceinline__ void vm_bar() {
  asm volatile("s_waitcnt vmcnt(0)" ::: "memory");
  __builtin_amdgcn_s_barrier();
  asm volatile("" ::: "memory");
}

// ---------------------------------------------------------------------------
// C[m,n] = sum_k A[m,k] * B[n,k]   (A: MxK bf16, B: NxK bf16 row-major)
// 128x128 tile, BK=32, 256 threads = 4 waves (2x2 of 64x64), 16x16x32 MFMA.
// 2-phase double-buffered: next-tile stage issued before current compute.
// ---------------------------------------------------------------------------
template <typename OUT>
__global__ __launch_bounds__(256) void gemm_bt(
    const unsigned short* __restrict__ A, const unsigned short* __restrict__ B,
    OUT* __restrict__ C, int M, int N, int K) {
  __shared__ unsigned short sA[2][128 * 32];
  __shared__ unsigned short sB[2][128 * 32];
  const int tid = threadIdx.x;
  const int wave = tid >> 6;
  const int lane = tid & 63;
  const int quad = lane >> 4;
  const int l15 = lane & 15;
  const int wm = (wave >> 1) * 64;
  const int wn = (wave & 1) * 64;
  const int bm = blockIdx.y * 128;
  const int bn = blockIdx.x * 128;

  float4v acc[4][4];
#pragma unroll
  for (int i = 0; i < 4; ++i)
#pragma unroll
    for (int j = 0; j < 4; ++j) acc[i][j] = (float4v){0.f, 0.f, 0.f, 0.f};

  const int srow = tid >> 2;
  const int scol = (tid & 3) * 8;
  const unsigned short* aptr = A + (size_t)(bm + srow) * K + scol;
  const unsigned short* bptr = B + (size_t)(bn + srow) * K + scol;
  const size_t astep = (size_t)64 * K;
  const int woff = wave * 512;

  // prologue: stage tile 0 into buf 0
  lds_load16(aptr, &sA[0][woff]);
  lds_load16(aptr + astep, &sA[0][2048 + woff]);
  lds_load16(bptr, &sB[0][woff]);
  lds_load16(bptr + astep, &sB[0][2048 + woff]);
  vm_bar();

  int cur = 0;
  for (int kt = 0; kt < K; kt += 32) {
    // issue next-tile stage first (latency hides under this tile's compute)
    if (kt + 32 < K) {
      const int nxt = cur ^ 1;
      lds_load16(aptr + kt + 32, &sA[nxt][woff]);
      lds_load16(aptr + kt + 32 + astep, &sA[nxt][2048 + woff]);
      lds_load16(bptr + kt + 32, &sB[nxt][woff]);
      lds_load16(bptr + kt + 32 + astep, &sB[nxt][2048 + woff]);
    }
    bf16x8 af[4], bf[4];
#pragma unroll
    for (int i = 0; i < 4; ++i)
      af[i] = *(const bf16x8*)&sA[cur][(wm + i * 16 + l15) * 32 + quad * 8];
#pragma unroll
    for (int j = 0; j < 4; ++j)
      bf[j] = *(const bf16x8*)&sB[cur][(wn + j * 16 + l15) * 32 + quad * 8];
#pragma unroll
    for (int i = 0; i < 4; ++i)
#pragma unroll
      for (int j = 0; j < 4; ++j)
        acc[i][j] = __builtin_amdgcn_mfma_f32_16x16x32_bf16(af[i], bf[j], acc[i][j], 0, 0, 0);
    // wait next-tile stage complete; sync all waves (reads of cur are retired
    // before the barrier via the MFMA data dependency).
    vm_bar();
    cur ^= 1;
  }

#pragma unroll
  for (int i = 0; i < 4; ++i) {
    const int row0 = bm + wm + i * 16 + quad * 4;
#pragma unroll
    for (int j = 0; j < 4; ++j) {
      const int col = bn + wn + j * 16 + l15;
#pragma unroll
      for (int r = 0; r < 4; ++r)
        store_out(&C[(size_t)(row0 + r) * N + col], acc[i][j][r]);
    }
  }
}

// ---------------------------------------------------------------------------
__global__ __launch_bounds__(256) void f32_to_bf16_k(const float* __restrict__ s,
                                                     unsigned short* __restrict__ d, int n) {
  const int i = (blockIdx.x * 256 + threadIdx.x) * 8;
  if (i >= n) return;
  const float4v a = *(const float4v*)(s + i);
  const float4v b = *(const float4v*)(s + i + 4);
  uint4v o;
  o[0] = (unsigned int)f2bf(a[0]) | ((unsigned int)f2bf(a[1]) << 16);
  o[1] = (unsigned int)f2bf(a[2]) | ((unsigned int)f2bf(a[3]) << 16);
  o[2] = (unsigned int)f2bf(b[0]) | ((unsigned int)f2bf(b[1]) << 16);
  o[3] = (unsigned int)f2bf(b[2]) | ((unsigned int)f2bf(b[3]) << 16);
  *(uint4v*)(d + i) = o;
}

// ---------------------------------------------------------------------------
// coeff[b,h,c,k] = sigmoid(ilr[row,h] + lb[h]) / (64*(k+1))
// ---------------------------------------------------------------------------
__global__ __launch_bounds__(256) void coeff_k(const unsigned short* __restrict__ ilr,
                                               const float* __restrict__ lb,
                                               float* __restrict__ coeff) {
  const int gid = blockIdx.x * 256 + threadIdx.x;
  const int row = gid >> 5;
  const int h = gid & 31;
  const float v = bf2f(ilr[row * 128 + h]) + lb[h];
  const float sig = 1.0f / (1.0f + __expf(-v));
  const int b = row >> 11;
  const int pos = row & 2047;
  const int cc = pos >> 4;
  const int k = pos & 15;
  coeff[((((size_t)b * 32 + h) * 128 + cc) << 4) + k] = sig / (64.0f * (float)(k + 1));
}

// ---------------------------------------------------------------------------
// TTT scan v4: one block = one (b,h); 4 waves; 128 sequential chunks of K=16.
// Wave w owns features w*16..w*16+15.
// ---------------------------------------------------------------------------
__global__ __launch_bounds__(256, 1) void ttt_scan(
    const unsigned short* __restrict__ XC, const unsigned short* __restrict__ XB,
    const unsigned short* __restrict__ XA, const float* __restrict__ coeff,
    const float* __restrict__ lnw, const float* __restrict__ lnb,
    const float* __restrict__ W1i, const float* __restrict__ b1i,
    unsigned short* __restrict__ XCW) {
  const int b = blockIdx.x >> 5;
  const int h = blockIdx.x & 31;
  const int tid = threadIdx.x;
  const int wave = tid >> 6;
  const int lane = tid & 63;
  const int quad = lane >> 4;
  const int l15 = lane & 15;

  // stride 88 u16 = 176 B: b128 reads stay 16B-aligned; row step = 44 dwords
  // = 12 banks mod 32 -> max 2-way conflicts (free).
  constexpr int LDW = 88;
  __shared__ __attribute__((aligned(16))) unsigned short sXC[2][16 * LDW];
  __shared__ __attribute__((aligned(16))) unsigned short sXB[2][16 * LDW];
  __shared__ __attribute__((aligned(16))) unsigned short sXA[2][16 * LDW];
  __shared__ __attribute__((aligned(16))) unsigned short sW1[64 * LDW];
  __shared__ __attribute__((aligned(16))) float sRed[3][16][8];  // [stage][token][wave*2+{a,b}]

  const int fcol = wave * 16 + l15;  // this lane's owned feature
  const float gam = lnw[h * 64 + fcol];
  const float bet = lnb[h * 64 + fcol];

  // W1 columns owned by this wave: W1r[mt][r] = W1[mt*16+quad*4+r][fcol]
  float4v W1r[4];
#pragma unroll
  for (int mt = 0; mt < 4; ++mt) {
    float4v v;
#pragma unroll
    for (int r = 0; r < 4; ++r)
      v[r] = W1i[(size_t)h * 4096 + (size_t)(mt * 16 + quad * 4 + r) * 64 + fcol];
    W1r[mt] = v;
  }
  float b1v = b1i[h * 64 + fcol];

  // initial publish of W1^T rows (wave-private rows [wave*16+l15])
#pragma unroll
  for (int mt = 0; mt < 4; ++mt) {
    uint2v p;
    p[0] = cvtpk_bf16(W1r[mt][0], W1r[mt][1]);
    p[1] = cvtpk_bf16(W1r[mt][2], W1r[mt][3]);
    *(uint2v*)&sW1[(size_t)fcol * LDW + mt * 16 + quad * 4] = p;
  }

  // staging unit: 16 rows x 8 col-chunks of 16B per tensor; threads 0-127
  // cover XC+XA, threads 128-255 cover XB.
  const int u = tid & 127;
  const int grow = u >> 3;
  const int gcol = (u & 7) * 8;
  const size_t hdoff = (size_t)h * 64;
  const size_t browoff = (size_t)b * 2048;
  const float* cobase = coeff + (((size_t)b * 32 + h) * 128) * 16;
  const float inv64 = 1.0f / 64.0f;
  const float4v zero4 = {0.f, 0.f, 0.f, 0.f};

  // ---- prefetch chunk 0 ----
  uint4v pA = {0, 0, 0, 0}, pB = {0, 0, 0, 0};
  float4v pcof;
  {
    const size_t goff = (browoff + (size_t)grow) * 2048 + hdoff + gcol;
    if (tid < 128) {
      pA = *(const uint4v*)(XC + goff);
      pB = *(const uint4v*)(XA + goff);
    } else {
      pA = *(const uint4v*)(XB + goff);
    }
    pcof = *(const float4v*)(cobase + quad * 4);  // coeff for tokens quad*4+0..3
  }

  for (int c = 0; c < 128; ++c) {
    const int buf = c & 1;
    // ---- write staged regs to LDS (vmcnt waits inserted by data dep) ----
    if (tid < 128) {
      *(uint4v*)&sXC[buf][grow * LDW + gcol] = pA;
      *(uint4v*)&sXA[buf][grow * LDW + gcol] = pB;
    } else {
      *(uint4v*)&sXB[buf][grow * LDW + gcol] = pA;
    }
    const float4v cof = pcof;  // cof[jj] = coeff for token quad*4+jj
    bar_sync();  // stage(c) + W1 publish visible

    // ---- issue prefetch for chunk c+1 (survives raw barriers) ----
    {
      const int cn = (c < 127) ? c + 1 : 127;
      const size_t goff = (browoff + (size_t)(cn * 16 + grow)) * 2048 + hdoff + gcol;
      if (tid < 128) {
        pA = *(const uint4v*)(XC + goff);
        pB = *(const uint4v*)(XA + goff);
      } else {
        pA = *(const uint4v*)(XB + goff);
      }
      pcof = *(const float4v*)(cobase + (size_t)cn * 16 + quad * 4);
    }

    // ---- fragments ----
    bf16x8 xbf[2], xcf[2], w1f[2];
#pragma unroll
    for (int hh = 0; hh < 2; ++hh) {
      xbf[hh] = *(const bf16x8*)&sXB[buf][l15 * LDW + hh * 32 + quad * 8];
      xcf[hh] = *(const bf16x8*)&sXC[buf][l15 * LDW + hh * 32 + quad * 8];
      w1f[hh] = *(const bf16x8*)&sW1[(size_t)fcol * LDW + hh * 32 + quad * 8];
    }

    // ---- Z1 = xb@W1[:,wave cols] + b1 ----
    float4v z = __builtin_amdgcn_mfma_f32_16x16x32_bf16(xbf[0], w1f[0], zero4, 0, 0, 0);
    z = __builtin_amdgcn_mfma_f32_16x16x32_bf16(xbf[1], w1f[1], z, 0, 0, 0);
#pragma unroll
    for (int r = 0; r < 4; ++r) z[r] += b1v;

    // ---- LN1 partials (per-wave feature slice) ----
    float s1p[4], s2p[4];
#pragma unroll
    for (int r = 0; r < 4; ++r) {
      s1p[r] = red16(z[r]);
      s2p[r] = red16(z[r] * z[r]);
    }
    if (l15 == 0) {
#pragma unroll
      for (int r = 0; r < 4; ++r)
        *(float2v*)&sRed[0][quad * 4 + r][wave * 2] = (float2v){s1p[r], s2p[r]};
    }

    // ---- Attn^T = xb@xc^T (indep of W1; hides under bar) ----
    float4v at = __builtin_amdgcn_mfma_f32_16x16x32_bf16(xbf[0], xcf[0], zero4, 0, 0, 0);
    at = __builtin_amdgcn_mfma_f32_16x16x32_bf16(xbf[1], xcf[1], at, 0, 0, 0);

    bar_sync();  // red1 partials visible

    float mu[4], rstd[4];
#pragma unroll
    for (int r = 0; r < 4; ++r) {
      const float4v v0 = *(const float4v*)&sRed[0][quad * 4 + r][0];
      const float4v v1 = *(const float4v*)&sRed[0][quad * 4 + r][4];
      const float s1 = v0[0] + v0[2] + v1[0] + v1[2];
      const float s2 = v0[1] + v0[3] + v1[1] + v1[3];
      mu[r] = s1 * inv64;
      rstd[r] = rsqrtf(s2 * inv64 - mu[r] * mu[r] + 1e-6f);
    }
    float xh[4], gg[4];
#pragma unroll
    for (int r = 0; r < 4; ++r) {
      xh[r] = (z[r] - mu[r]) * rstd[r];
      const int toff = (quad * 4 + r) * LDW + fcol;
      const float tgt = bf2f(sXA[buf][toff]) - bf2f(sXB[buf][toff]);
      gg[r] = (gam * xh[r] + bet - tgt) * gam;
    }
    float sgp[4], sgxp[4];
#pragma unroll
    for (int r = 0; r < 4; ++r) {
      sgp[r] = red16(gg[r]);
      sgxp[r] = red16(gg[r] * xh[r]);
    }
    if (l15 == 0) {
#pragma unroll
      for (int r = 0; r < 4; ++r)
        *(float2v*)&sRed[1][quad * 4 + r][wave * 2] = (float2v){sgp[r], sgxp[r]};
    }

    // ---- indep work under bar2: caf (W1-update A-frag), m1f ----
    short4v caf[4];
#pragma unroll
    for (int mt = 0; mt < 4; ++mt)
#pragma unroll
      for (int jj = 0; jj < 4; ++jj)
        caf[mt][jj] =
            (short)f2bf(-cof[jj] * bf2f(sXB[buf][(quad * 4 + jj) * LDW + mt * 16 + l15]));
    short4v m1f;
#pragma unroll
    for (int jj = 0; jj < 4; ++jj) {
      const int k = quad * 4 + jj;
      const float e = (k <= l15) ? cof[jj] : 0.0f;
      m1f[jj] = (short)f2bf(-(at[jj] + 1.0f) * e);
    }

    bar_sync();  // red2 partials visible

    float grad[4];
    short4v gradb;
#pragma unroll
    for (int r = 0; r < 4; ++r) {
      const float4v v0 = *(const float4v*)&sRed[1][quad * 4 + r][0];
      const float4v v1 = *(const float4v*)&sRed[1][quad * 4 + r][4];
      const float sg = v0[0] + v0[2] + v1[0] + v1[2];
      const float sgx = v0[1] + v0[3] + v1[1] + v1[3];
      grad[r] = (64.0f * gg[r] - sg - xh[r] * sgx) * (rstd[r] * inv64);
      gradb[r] = (short)f2bf(grad[r]);
    }

    // ---- Z1_bar = xc@W1 - ((Attn+1) o E)@grad + b1 (old b1) ----
    float4v zb = __builtin_amdgcn_mfma_f32_16x16x32_bf16(xcf[0], w1f[0], zero4, 0, 0, 0);
    zb = __builtin_amdgcn_mfma_f32_16x16x32_bf16(xcf[1], w1f[1], zb, 0, 0, 0);
    zb = __builtin_amdgcn_mfma_f32_16x16x16bf16_1k(m1f, gradb, zb, 0, 0, 0);
#pragma unroll
    for (int r = 0; r < 4; ++r) zb[r] += b1v;

    // ---- LN2 partials ----
#pragma unroll
    for (int r = 0; r < 4; ++r) {
      s1p[r] = red16(zb[r]);
      s2p[r] = red16(zb[r] * zb[r]);
    }
    if (l15 == 0) {
#pragma unroll
      for (int r = 0; r < 4; ++r)
        *(float2v*)&sRed[2][quad * 4 + r][wave * 2] = (float2v){s1p[r], s2p[r]};
    }

    // ---- indep work under bar3: b1 update + W1 update MFMAs ----
    {
      float pb = cof[0] * grad[0] + cof[1] * grad[1] + cof[2] * grad[2] + cof[3] * grad[3];
      pb += __shfl_xor(pb, 16);
      pb += __shfl_xor(pb, 32);
      b1v -= pb;
    }
#pragma unroll
    for (int mt = 0; mt < 4; ++mt)
      W1r[mt] = __builtin_amdgcn_mfma_f32_16x16x16bf16_1k(caf[mt], gradb, W1r[mt], 0, 0, 0);

    bar_sync();  // red3 partials visible

#pragma unroll
    for (int r = 0; r < 4; ++r) {
      const float4v v0 = *(const float4v*)&sRed[2][quad * 4 + r][0];
      const float4v v1 = *(const float4v*)&sRed[2][quad * 4 + r][4];
      const float s1 = v0[0] + v0[2] + v1[0] + v1[2];
      const float s2 = v0[1] + v0[3] + v1[1] + v1[3];
      const float mu2 = s1 * inv64;
      const float rstd2 = rsqrtf(s2 * inv64 - mu2 * mu2 + 1e-6f);
      const float xhat = (zb[r] - mu2) * rstd2;
      const float y = gam * xhat + bet;
      const float o = bf2f(sXC[buf][(quad * 4 + r) * LDW + fcol]) + y;
      XCW[(browoff + (size_t)(c * 16 + quad * 4 + r)) * 2048 + hdoff + fcol] = f2bf(o);
    }

    // ---- publish updated W1 for next chunk (wave-private rows) ----
#pragma unroll
    for (int mt = 0; mt < 4; ++mt) {
      uint2v p;
      p[0] = cvtpk_bf16(W1r[mt][0], W1r[mt][1]);
      p[1] = cvtpk_bf16(W1r[mt][2], W1r[mt][3]);
      *(uint2v*)&sW1[(size_t)fcol * LDW + mt * 16 + quad * 4] = p;
    }
  }
}

// ---------------------------------------------------------------------------
extern "C" void kernel_launch(void* const* d_in, const int* in_sizes, int n_in,
                              void* d_out, int out_size, void* d_ws, size_t ws_size,
                              hipStream_t stream) {
  const float* hs = (const float*)d_in[0];
  const float* Wq = (const float*)d_in[1];
  const float* Wk = (const float*)d_in[2];
  const float* Wv = (const float*)d_in[3];
  const float* Wo = (const float*)d_in[4];
  const float* lw = (const float*)d_in[5];
  const float* lb = (const float*)d_in[6];
  const float* lnw = (const float*)d_in[7];
  const float* lnb = (const float*)d_in[8];
  const float* W1i = (const float*)d_in[9];
  const float* b1i = (const float*)d_in[10];
  float* out = (float*)d_out;
  char* ws = (char*)d_ws;

  unsigned short* hsb = (unsigned short*)(ws);               // 33554432 (hs bf16; reused as XCW)
  unsigned short* wqb = (unsigned short*)(ws + 33554432);    // 8388608
  unsigned short* wkb = (unsigned short*)(ws + 41943040);    // 8388608
  unsigned short* wvb = (unsigned short*)(ws + 50331648);    // 8388608
  unsigned short* wob = (unsigned short*)(ws + 58720256);    // 8388608
  unsigned short* lwb = (unsigned short*)(ws + 67108864);    // 524288
  unsigned short* XCb = (unsigned short*)(ws + 67633152);    // 33554432
  unsigned short* XBb = (unsigned short*)(ws + 101187584);   // 33554432
  unsigned short* XAb = (unsigned short*)(ws + 134742016);   // 33554432
  unsigned short* ilrb = (unsigned short*)(ws + 168296448);  // 2097152
  float* coeff = (float*)(ws + 170393600);                   // 1048576

  f32_to_bf16_k<<<8192, 256, 0, stream>>>(hs, hsb, 16777216);
  f32_to_bf16_k<<<2048, 256, 0, stream>>>(Wq, wqb, 4194304);
  f32_to_bf16_k<<<2048, 256, 0, stream>>>(Wk, wkb, 4194304);
  f32_to_bf16_k<<<2048, 256, 0, stream>>>(Wv, wvb, 4194304);
  f32_to_bf16_k<<<2048, 256, 0, stream>>>(Wo, wob, 4194304);
  hipMemsetAsync(lwb, 0, 524288, stream);
  f32_to_bf16_k<<<32, 256, 0, stream>>>(lw, lwb, 65536);

  dim3 blk(256);
  dim3 gbig(16, 64);
  gemm_bt<unsigned short><<<gbig, blk, 0, stream>>>(hsb, wqb, XCb, 8192, 2048, 2048);
  gemm_bt<unsigned short><<<gbig, blk, 0, stream>>>(hsb, wkb, XBb, 8192, 2048, 2048);
  gemm_bt<unsigned short><<<gbig, blk, 0, stream>>>(hsb, wvb, XAb, 8192, 2048, 2048);
  gemm_bt<unsigned short><<<dim3(1, 64), blk, 0, stream>>>(hsb, lwb, ilrb, 8192, 128, 2048);
  coeff_k<<<1024, 256, 0, stream>>>(ilrb, lb, coeff);
  ttt_scan<<<128, 256, 0, stream>>>(XCb, XBb, XAb, coeff, lnw, lnb, W1i, b1i, hsb);
  gemm_bt<float><<<gbig, blk, 0, stream>>>(hsb, wob, out, 8192, 2048, 2048);
}